// Round 1
// baseline (226.232 us; speedup 1.0000x reference)
//
#include <hip/hip_runtime.h>

#define BLOCK 256

__global__ __launch_bounds__(BLOCK) void gauss_cov_kernel(
    const float4* __restrict__ quat,
    const float4* __restrict__ log_scale4,   // same buffer viewed as float4
    const float*  __restrict__ log_scale,    // scalar view for tail
    float4*       __restrict__ out4,         // output viewed as float4
    float*        __restrict__ out,          // scalar view for tail
    int n)
{
    __shared__ __align__(16) float sm[BLOCK * 9];
    const int tid = threadIdx.x;
    const long long i = (long long)blockIdx.x * BLOCK + tid;
    const bool full_block = ((long long)(blockIdx.x + 1) * BLOCK) <= (long long)n;

    // ---- load log_scale: 192 float4 per block (16B/lane), repack via LDS ----
    float ls0 = 0.f, ls1 = 0.f, ls2 = 0.f;
    if (full_block) {
        if (tid < (BLOCK * 3 / 4)) {   // 192 threads each load one float4
            const float4 v = log_scale4[(long long)blockIdx.x * (BLOCK * 3 / 4) + tid];
            *reinterpret_cast<float4*>(&sm[tid * 4]) = v;
        }
        __syncthreads();
        // stride-3 dword reads: gcd(3,32)=1 -> <=2-way bank aliasing (free)
        ls0 = sm[tid * 3 + 0];
        ls1 = sm[tid * 3 + 1];
        ls2 = sm[tid * 3 + 2];
        __syncthreads();
    } else if (i < n) {
        ls0 = log_scale[3 * i + 0];
        ls1 = log_scale[3 * i + 1];
        ls2 = log_scale[3 * i + 2];
    }

    // ---- load quaternion (float4, coalesced, 16B/lane) ----
    float c[9];
    if (i < n) {
        const float4 q4 = quat[i];
        const float dot = q4.x * q4.x + q4.y * q4.y + q4.z * q4.z + q4.w * q4.w;
        const float norm = sqrtf(dot);
        const float inv = 1.0f / fmaxf(norm, 1e-12f);
        const float qw = q4.x * inv;
        const float qx = q4.y * inv;
        const float qy = q4.z * inv;
        const float qz = q4.w * inv;

        const float r00 = 1.f - 2.f * (qy * qy + qz * qz);
        const float r01 = 2.f * (qx * qy - qz * qw);
        const float r02 = 2.f * (qx * qz + qy * qw);
        const float r10 = 2.f * (qx * qy + qz * qw);
        const float r11 = 1.f - 2.f * (qx * qx + qz * qz);
        const float r12 = 2.f * (qy * qz - qx * qw);
        const float r20 = 2.f * (qx * qz - qy * qw);
        const float r21 = 2.f * (qy * qz + qx * qw);
        const float r22 = 1.f - 2.f * (qx * qx + qy * qy);

        const float s0 = expf(ls0);
        const float s1 = expf(ls1);
        const float s2 = expf(ls2);

        // cov[i][k] = sum_j s_j * R[i][j] * R[k][j]
        c[0] = s0 * r00 * r00 + s1 * r01 * r01 + s2 * r02 * r02;
        c[1] = s0 * r00 * r10 + s1 * r01 * r11 + s2 * r02 * r12;
        c[2] = s0 * r00 * r20 + s1 * r01 * r21 + s2 * r02 * r22;
        c[3] = c[1];
        c[4] = s0 * r10 * r10 + s1 * r11 * r11 + s2 * r12 * r12;
        c[5] = s0 * r10 * r20 + s1 * r11 * r21 + s2 * r12 * r22;
        c[6] = c[2];
        c[7] = c[5];
        c[8] = s0 * r20 * r20 + s1 * r21 * r21 + s2 * r22 * r22;
    }

    // ---- store covariance: LDS repack -> float4 global stores (16B/lane) ----
    if (full_block) {
        // stride-9 dword writes: gcd(9,32)=1 -> <=2-way bank aliasing (free)
        #pragma unroll
        for (int j = 0; j < 9; ++j)
            sm[tid * 9 + j] = c[j];
        __syncthreads();
        // drain 2304 floats = 576 float4 with fully-coalesced dwordx4 stores
        const long long base4 = (long long)blockIdx.x * (BLOCK * 9 / 4);  // 576
        float4* __restrict__ dst = out4 + base4;
        const float4* __restrict__ src = reinterpret_cast<const float4*>(sm);
        dst[tid]         = src[tid];          // consecutive b128 LDS reads: standard, conflict-free
        dst[BLOCK + tid] = src[BLOCK + tid];
        if (tid < (BLOCK * 9 / 4 - 2 * BLOCK))  // 64 threads finish the last 64 float4
            dst[2 * BLOCK + tid] = src[2 * BLOCK + tid];
    } else if (i < n) {
        #pragma unroll
        for (int j = 0; j < 9; ++j)
            out[i * 9 + j] = c[j];
    }
}

extern "C" void kernel_launch(void* const* d_in, const int* in_sizes, int n_in,
                              void* d_out, int out_size, void* d_ws, size_t ws_size,
                              hipStream_t stream) {
    const float4* quat       = (const float4*)d_in[0];
    const float4* log_scale4 = (const float4*)d_in[1];
    const float*  log_scale  = (const float*)d_in[1];
    float4*       out4       = (float4*)d_out;
    float*        out        = (float*)d_out;
    const int n = in_sizes[0] / 4;  // quaternion is (N,4)

    const int grid = (n + BLOCK - 1) / BLOCK;
    gauss_cov_kernel<<<grid, BLOCK, 0, stream>>>(quat, log_scale4, log_scale,
                                                 out4, out, n);
}

// Round 2
// 219.521 us; speedup vs baseline: 1.0306x; 1.0306x over previous
//
#include <hip/hip_runtime.h>

#define BLOCK 256
#define MAX_GRID 2048   // 256 CUs x 8 blocks/CU; grid-stride the rest (G11)

typedef float vfloat4 __attribute__((ext_vector_type(4)));

__global__ __launch_bounds__(BLOCK) void gauss_cov_kernel(
    const vfloat4* __restrict__ quat,
    const vfloat4* __restrict__ log_scale4,   // same buffer viewed as float4
    const float*   __restrict__ log_scale,    // scalar view for tail
    vfloat4*       __restrict__ out4,         // output viewed as float4
    float*         __restrict__ out,          // scalar view for tail
    int n, int ntiles)
{
    __shared__ __align__(16) float sm_ls[BLOCK * 3];
    __shared__ __align__(16) float sm_out[BLOCK * 9];
    const int tid = threadIdx.x;

    for (int tile = blockIdx.x; tile < ntiles; tile += gridDim.x) {
        const long long i = (long long)tile * BLOCK + tid;
        // tile-uniform: no divergent-barrier hazard
        const bool full = ((long long)(tile + 1) * BLOCK) <= (long long)n;

        // ---- load log_scale: 192 nt float4 loads (16B/lane), repack via LDS ----
        float ls0 = 0.f, ls1 = 0.f, ls2 = 0.f;
        if (full) {
            if (tid < (BLOCK * 3 / 4)) {
                const vfloat4 v = __builtin_nontemporal_load(
                    &log_scale4[(long long)tile * (BLOCK * 3 / 4) + tid]);
                *reinterpret_cast<vfloat4*>(&sm_ls[tid * 4]) = v;
            }
            // barrier A: makes sm_ls visible; also fences previous tile's
            // sm_out drain-reads against this tile's sm_out writes below
            __syncthreads();
            // stride-3 reads: gcd(3,32)=1 -> <=2-way bank aliasing (free, m136)
            ls0 = sm_ls[tid * 3 + 0];
            ls1 = sm_ls[tid * 3 + 1];
            ls2 = sm_ls[tid * 3 + 2];
        } else if (i < n) {
            ls0 = log_scale[3 * i + 0];
            ls1 = log_scale[3 * i + 1];
            ls2 = log_scale[3 * i + 2];
        }

        // ---- load quaternion (nt float4, coalesced, 16B/lane) ----
        float c[9];
        if (i < n) {
            const vfloat4 q4 = __builtin_nontemporal_load(&quat[i]);
            const float dot = q4.x * q4.x + q4.y * q4.y + q4.z * q4.z + q4.w * q4.w;
            const float norm = sqrtf(dot);
            const float inv = 1.0f / fmaxf(norm, 1e-12f);
            const float qw = q4.x * inv;
            const float qx = q4.y * inv;
            const float qy = q4.z * inv;
            const float qz = q4.w * inv;

            const float r00 = 1.f - 2.f * (qy * qy + qz * qz);
            const float r01 = 2.f * (qx * qy - qz * qw);
            const float r02 = 2.f * (qx * qz + qy * qw);
            const float r10 = 2.f * (qx * qy + qz * qw);
            const float r11 = 1.f - 2.f * (qx * qx + qz * qz);
            const float r12 = 2.f * (qy * qz - qx * qw);
            const float r20 = 2.f * (qx * qz - qy * qw);
            const float r21 = 2.f * (qy * qz + qx * qw);
            const float r22 = 1.f - 2.f * (qx * qx + qy * qy);

            const float s0 = expf(ls0);
            const float s1 = expf(ls1);
            const float s2 = expf(ls2);

            // cov[i][k] = sum_j s_j * R[i][j] * R[k][j]
            c[0] = s0 * r00 * r00 + s1 * r01 * r01 + s2 * r02 * r02;
            c[1] = s0 * r00 * r10 + s1 * r01 * r11 + s2 * r02 * r12;
            c[2] = s0 * r00 * r20 + s1 * r01 * r21 + s2 * r02 * r22;
            c[3] = c[1];
            c[4] = s0 * r10 * r10 + s1 * r11 * r11 + s2 * r12 * r12;
            c[5] = s0 * r10 * r20 + s1 * r11 * r21 + s2 * r12 * r22;
            c[6] = c[2];
            c[7] = c[5];
            c[8] = s0 * r20 * r20 + s1 * r21 * r21 + s2 * r22 * r22;
        }

        // ---- store covariance: LDS repack -> nt float4 global stores ----
        if (full) {
            // stride-9 writes: gcd(9,32)=1 -> <=2-way bank aliasing (free)
            #pragma unroll
            for (int j = 0; j < 9; ++j)
                sm_out[tid * 9 + j] = c[j];
            __syncthreads();   // barrier B: sm_out visible for drain
            const long long base4 = (long long)tile * (BLOCK * 9 / 4);  // 576/tile
            vfloat4* __restrict__ dst = out4 + base4;
            const vfloat4* __restrict__ src =
                reinterpret_cast<const vfloat4*>(sm_out);
            __builtin_nontemporal_store(src[tid],         &dst[tid]);
            __builtin_nontemporal_store(src[BLOCK + tid], &dst[BLOCK + tid]);
            if (tid < (BLOCK * 9 / 4 - 2 * BLOCK))   // last 64 float4
                __builtin_nontemporal_store(src[2 * BLOCK + tid],
                                            &dst[2 * BLOCK + tid]);
            // no trailing barrier: next iteration's barrier A fences the
            // drain-reads before sm_out is overwritten
        } else if (i < n) {
            #pragma unroll
            for (int j = 0; j < 9; ++j)
                out[i * 9 + j] = c[j];
        }
    }
}

extern "C" void kernel_launch(void* const* d_in, const int* in_sizes, int n_in,
                              void* d_out, int out_size, void* d_ws, size_t ws_size,
                              hipStream_t stream) {
    const vfloat4* quat       = (const vfloat4*)d_in[0];
    const vfloat4* log_scale4 = (const vfloat4*)d_in[1];
    const float*   log_scale  = (const float*)d_in[1];
    vfloat4*       out4       = (vfloat4*)d_out;
    float*         out        = (float*)d_out;
    const int n = in_sizes[0] / 4;  // quaternion is (N,4)

    const int ntiles = (n + BLOCK - 1) / BLOCK;
    const int grid = ntiles < MAX_GRID ? ntiles : MAX_GRID;
    gauss_cov_kernel<<<grid, BLOCK, 0, stream>>>(quat, log_scale4, log_scale,
                                                 out4, out, n, ntiles);
}